// Round 3
// baseline (578.372 us; speedup 1.0000x reference)
//
#include <hip/hip_runtime.h>
#include <cstdint>
#include <cstddef>

// Problem constants
#define B_SZ      2
#define S_LEN     2048
#define HID_DIM   1024
#define N_HEAD    16
#define D_HEAD    64
#define INNER_DIM 1024

// scale constants: scores = (s + bias)/8 + mask, softmax in exp2 space
// fold 0.125*log2(e) into Q at projection time; fused bias = bias*C1 + mask*C2
#define C1 0.18033688011112042f    /* 0.125 * log2(e) */
#define C2 1.44269504088896340736f /* log2(e) */

typedef __attribute__((ext_vector_type(8))) short bf16x8;   // 8 x bf16 (4 VGPRs)
typedef __attribute__((ext_vector_type(4))) float f32x4;    // MFMA 16x16 C/D

__device__ __forceinline__ unsigned short f2bf(float f) {
  unsigned int u = __float_as_uint(f);
  u += 0x7fffu + ((u >> 16) & 1u);
  return (unsigned short)(u >> 16);
}
__device__ __forceinline__ float bf2f(unsigned short u) {
  return __uint_as_float(((unsigned int)u) << 16);
}

// async global->LDS, 16B per lane; dest = wave-uniform base + lane*16
__device__ __forceinline__ void gload_lds16(const void* g, void* l) {
  __builtin_amdgcn_global_load_lds((const __attribute__((address_space(1))) void*)g,
                                   (__attribute__((address_space(3))) void*)l,
                                   16, 0, 0);
}

// ---------------------------------------------------------------- cast fp32->bf16 (x3)
__global__ void cast3_kernel(const float* __restrict__ i0, const float* __restrict__ i1,
                             const float* __restrict__ i2,
                             unsigned short* __restrict__ o0, unsigned short* __restrict__ o1,
                             unsigned short* __restrict__ o2, int n4) {
  int z = blockIdx.y;
  const float* in = (z == 0) ? i0 : (z == 1) ? i1 : i2;
  unsigned short* out = (z == 0) ? o0 : (z == 1) ? o1 : o2;
  int i = blockIdx.x * blockDim.x + threadIdx.x;
  if (i < n4) {
    float4 v = ((const float4*)in)[i];
    ushort4 o;
    o.x = f2bf(v.x); o.y = f2bf(v.y); o.z = f2bf(v.z); o.w = f2bf(v.w);
    ((ushort4*)out)[i] = o;
  }
}

// ------------------------------------------- transpose + cast: W[K][N] -> Wt[N][K] bf16
__global__ void transpose_cast_kernel(const float* __restrict__ in,
                                      unsigned short* __restrict__ out,
                                      int rows, int cols) {
  __shared__ float tile[32][33];
  int bx = blockIdx.x * 32;
  int by = blockIdx.y * 32;
  int tx = threadIdx.x & 31;
  int ty = threadIdx.x >> 5;
#pragma unroll
  for (int i = 0; i < 32; i += 8)
    tile[ty + i][tx] = in[(size_t)(by + ty + i) * cols + bx + tx];
  __syncthreads();
#pragma unroll
  for (int i = 0; i < 32; i += 8)
    out[(size_t)(bx + ty + i) * rows + by + tx] = f2bf(tile[tx][ty + i]);
}

// ---------------------------------------------------------------- GEMM core
// A: [M][1024] bf16 row-major.  Bt: [N][1024] bf16 row-major.
// Tile 128(M) x 64(N) x 64(K); 256 thr = 4 waves (2x2), wave does 64x32.
// LDS XOR-swizzle: 16B segment stored at seg ^ (row & 7).

// Merged Q/K/V projection GEMM. z = blockIdx.z selects problem.
// z<2: bf16 row-major out (z==0 scaled by C1).  z==2: V, store transposed [B][H][D][S].
__global__ __launch_bounds__(256, 2)
void qkv_gemm_kernel(const unsigned short* __restrict__ Aq,
                     const unsigned short* __restrict__ Ak,
                     const unsigned short* __restrict__ Av,
                     const unsigned short* __restrict__ Wq,
                     const unsigned short* __restrict__ Wk,
                     const unsigned short* __restrict__ Wv,
                     const float* __restrict__ bq,
                     const float* __restrict__ bk,
                     const float* __restrict__ bv,
                     unsigned short* __restrict__ Oq,
                     unsigned short* __restrict__ Ok,
                     unsigned short* __restrict__ Ov) {
  constexpr int K = 1024;
  __shared__ unsigned short Asm[128 * 64];
  __shared__ unsigned short Bsm[64 * 64];

  const int z = blockIdx.z;
  const unsigned short* A  = (z == 0) ? Aq : (z == 1) ? Ak : Av;
  const unsigned short* Bt = (z == 0) ? Wq : (z == 1) ? Wk : Wv;
  const float* bias        = (z == 0) ? bq : (z == 1) ? bk : bv;
  const float scale        = (z == 0) ? C1 : 1.0f;

  const int tid = threadIdx.x;
  const int lane = tid & 63;
  const int w = tid >> 6;
  const int wm = w & 1;
  const int wn = w >> 1;
  const int c = lane & 15;
  const int g = lane >> 4;
  const int m0 = blockIdx.x * 128;
  const int n0 = blockIdx.y * 64;

  f32x4 acc[4][2];
  f32x4 zero = {0.f, 0.f, 0.f, 0.f};
#pragma unroll
  for (int mt = 0; mt < 4; ++mt)
#pragma unroll
    for (int nt = 0; nt < 2; ++nt) acc[mt][nt] = zero;

  for (int kk = 0; kk < K / 64; ++kk) {
    __syncthreads();
    const int k0 = kk * 64;
#pragma unroll
    for (int it = 0; it < 4; ++it) {
      int slot = it * 256 + tid;
      int r = slot >> 3, sp = slot & 7, seg = sp ^ (r & 7);
      gload_lds16(A + (size_t)(m0 + r) * K + k0 + seg * 8,
                  (char*)Asm + (it * 256 + w * 64) * 16);
    }
#pragma unroll
    for (int it = 0; it < 2; ++it) {
      int slot = it * 256 + tid;
      int r = slot >> 3, sp = slot & 7, seg = sp ^ (r & 7);
      gload_lds16(Bt + (size_t)(n0 + r) * K + k0 + seg * 8,
                  (char*)Bsm + (it * 256 + w * 64) * 16);
    }
    __syncthreads();

#pragma unroll
    for (int ks = 0; ks < 2; ++ks) {
      bf16x8 aF[4];
#pragma unroll
      for (int mt = 0; mt < 4; ++mt) {
        int r = wm * 64 + mt * 16 + c;
        int seg = (ks * 4 + g) ^ (r & 7);
        aF[mt] = *(const bf16x8*)((const char*)Asm + r * 128 + seg * 16);
      }
#pragma unroll
      for (int nt = 0; nt < 2; ++nt) {
        int r = wn * 32 + nt * 16 + c;
        int seg = (ks * 4 + g) ^ (r & 7);
        bf16x8 bF = *(const bf16x8*)((const char*)Bsm + r * 128 + seg * 16);
#pragma unroll
        for (int mt = 0; mt < 4; ++mt)
          acc[mt][nt] = __builtin_amdgcn_mfma_f32_16x16x32_bf16(aF[mt], bF, acc[mt][nt], 0, 0, 0);
      }
    }
  }

#pragma unroll
  for (int nt = 0; nt < 2; ++nt) {
    int n_g = n0 + wn * 32 + nt * 16 + c;
    float bvv = bias[n_g];
#pragma unroll
    for (int mt = 0; mt < 4; ++mt) {
      int m_base = m0 + wm * 64 + mt * 16 + g * 4;
      if (z == 2) {
        int b = m_base >> 11;
        int s = m_base & 2047;
        int hh = n_g >> 6;
        int d = n_g & 63;
        ushort4 pk;
        pk.x = f2bf(acc[mt][nt][0] + bvv);
        pk.y = f2bf(acc[mt][nt][1] + bvv);
        pk.z = f2bf(acc[mt][nt][2] + bvv);
        pk.w = f2bf(acc[mt][nt][3] + bvv);
        *(ushort4*)(Ov + ((size_t)((b * N_HEAD + hh) * D_HEAD + d)) * S_LEN + s) = pk;
      } else {
        unsigned short* o = (z == 0) ? Oq : Ok;
#pragma unroll
        for (int r = 0; r < 4; ++r)
          o[(size_t)(m_base + r) * INNER_DIM + n_g] = f2bf((acc[mt][nt][r] + bvv) * scale);
      }
    }
  }
}

// Out-projection GEMM: fp32 out.
__global__ __launch_bounds__(256, 2)
void out_gemm_kernel(const unsigned short* __restrict__ A,
                     const unsigned short* __restrict__ Bt,
                     const float* __restrict__ bias,
                     float* __restrict__ out) {
  constexpr int K = 1024;
  __shared__ unsigned short Asm[128 * 64];
  __shared__ unsigned short Bsm[64 * 64];

  const int tid = threadIdx.x;
  const int lane = tid & 63;
  const int w = tid >> 6;
  const int wm = w & 1;
  const int wn = w >> 1;
  const int c = lane & 15;
  const int g = lane >> 4;
  const int m0 = blockIdx.x * 128;
  const int n0 = blockIdx.y * 64;

  f32x4 acc[4][2];
  f32x4 zero = {0.f, 0.f, 0.f, 0.f};
#pragma unroll
  for (int mt = 0; mt < 4; ++mt)
#pragma unroll
    for (int nt = 0; nt < 2; ++nt) acc[mt][nt] = zero;

  for (int kk = 0; kk < K / 64; ++kk) {
    __syncthreads();
    const int k0 = kk * 64;
#pragma unroll
    for (int it = 0; it < 4; ++it) {
      int slot = it * 256 + tid;
      int r = slot >> 3, sp = slot & 7, seg = sp ^ (r & 7);
      gload_lds16(A + (size_t)(m0 + r) * K + k0 + seg * 8,
                  (char*)Asm + (it * 256 + w * 64) * 16);
    }
#pragma unroll
    for (int it = 0; it < 2; ++it) {
      int slot = it * 256 + tid;
      int r = slot >> 3, sp = slot & 7, seg = sp ^ (r & 7);
      gload_lds16(Bt + (size_t)(n0 + r) * K + k0 + seg * 8,
                  (char*)Bsm + (it * 256 + w * 64) * 16);
    }
    __syncthreads();

#pragma unroll
    for (int ks = 0; ks < 2; ++ks) {
      bf16x8 aF[4];
#pragma unroll
      for (int mt = 0; mt < 4; ++mt) {
        int r = wm * 64 + mt * 16 + c;
        int seg = (ks * 4 + g) ^ (r & 7);
        aF[mt] = *(const bf16x8*)((const char*)Asm + r * 128 + seg * 16);
      }
#pragma unroll
      for (int nt = 0; nt < 2; ++nt) {
        int r = wn * 32 + nt * 16 + c;
        int seg = (ks * 4 + g) ^ (r & 7);
        bf16x8 bF = *(const bf16x8*)((const char*)Bsm + r * 128 + seg * 16);
#pragma unroll
        for (int mt = 0; mt < 4; ++mt)
          acc[mt][nt] = __builtin_amdgcn_mfma_f32_16x16x32_bf16(aF[mt], bF, acc[mt][nt], 0, 0, 0);
      }
    }
  }

#pragma unroll
  for (int nt = 0; nt < 2; ++nt) {
    int n_g = n0 + wn * 32 + nt * 16 + c;
    float bvv = bias[n_g];
#pragma unroll
    for (int mt = 0; mt < 4; ++mt) {
      int m_base = m0 + wm * 64 + mt * 16 + g * 4;
#pragma unroll
      for (int r = 0; r < 4; ++r)
        out[(size_t)(m_base + r) * HID_DIM + n_g] = acc[mt][nt][r] + bvv;
    }
  }
}

// ---------------------------------------------------------------- flash attention
// q-tile 64, 256 thr = 4 waves (wave w owns q rows w*16..w*16+15); kv-tile 64.
// LDS: K dbuf 2x8K + V dbuf 2x8K + P 8K = 40 KB -> 4 independent blocks/CU
// (16 waves/CU, 4/SIMD): one block's barrier/vmcnt drain hides under the other
// three blocks' compute.  Softmax: m==0 (scores tightly bounded; shift-invariant
// exactness), deferred l-reduce -> zero cross-lane ops in the k-loop.
// Bias AND mask are register-prefetched one kv-tile ahead in the consume layout
// (scalar dword loads: row g*4+r, col nt*16+c -> 4x64B sectors/instr).
__global__ __launch_bounds__(256, 4)
void attn_kernel(const unsigned short* __restrict__ Qp,
                 const unsigned short* __restrict__ Kp,
                 const unsigned short* __restrict__ Vp,
                 const float* __restrict__ bias,   // [1][H][S][S]
                 const float* __restrict__ mask,   // [B][1][S][S]
                 unsigned short* __restrict__ Osm) {
  __shared__ unsigned short Ksm0[64 * 64];    // [kv][d]  NSEG8 swizzle   8 KB
  __shared__ unsigned short Ksm1[64 * 64];
  __shared__ unsigned short Vsm0[64 * 64];    // [d][kv]  NSEG8 swizzle   8 KB
  __shared__ unsigned short Vsm1[64 * 64];
  __shared__ unsigned short Psm[64 * 64];     // [q][kv]  wave-private    8 KB

  const int tid = threadIdx.x;
  const int lane = tid & 63;
  const int w = tid >> 6;           // wave 0..3
  const int c = lane & 15;
  const int g = lane >> 4;
  const int q0 = blockIdx.x * 64;
  const int h = blockIdx.y;
  const int b = blockIdx.z;

  char* Pw = (char*)Psm + w * 2048;     // wave-private 16 rows x 128 B

  // Q fragments (A-layout: m=c, k=g*8+j), rows w*16+c
  bf16x8 qF[2];
  {
    size_t row = (size_t)(b * S_LEN + q0 + w * 16 + c);
#pragma unroll
    for (int ks = 0; ks < 2; ++ks)
      qF[ks] = *(const bf16x8*)(Qp + row * INNER_DIM + h * D_HEAD + ks * 32 + g * 8);
  }

  // per-lane bias/mask bases in CONSUME layout: row = g*4 (+r), col = c (+nt*16)
  const float* bias_base = bias + ((size_t)h * S_LEN + q0 + w * 16 + g * 4) * S_LEN + c;
  const float* mask_base = mask + ((size_t)b * S_LEN + q0 + w * 16 + g * 4) * S_LEN + c;

  // j-invariant staging sources (swizzled source addr, linear LDS dest)
  const unsigned short* kSrc[2];
  const unsigned short* vSrc[2];
#pragma unroll
  for (int it = 0; it < 2; ++it) {
    int slot = it * 256 + tid;
    int r = slot >> 3, sp = slot & 7, seg = sp ^ (r & 7);
    kSrc[it] = Kp + (size_t)(b * S_LEN + r) * INNER_DIM + h * D_HEAD + seg * 8;
    vSrc[it] = Vp + ((size_t)((b * N_HEAD + h) * D_HEAD + r)) * S_LEN + seg * 8;
  }

  auto STAGE = [&](int jt, unsigned short* Kd, unsigned short* Vd) {
#pragma unroll
    for (int it = 0; it < 2; ++it)
      gload_lds16(kSrc[it] + (size_t)jt * (64 * INNER_DIM),
                  (char*)Kd + (it * 256 + w * 64) * 16);
#pragma unroll
    for (int it = 0; it < 2; ++it)
      gload_lds16(vSrc[it] + jt * 64,
                  (char*)Vd + (it * 256 + w * 64) * 16);
  };

  float bpre[16], mpre[16];             // bias/mask prefetch, one tile ahead
  auto BM_PRE = [&](int jt) {
#pragma unroll
    for (int nt = 0; nt < 4; ++nt)
#pragma unroll
      for (int r = 0; r < 4; ++r) {
        bpre[nt * 4 + r] = bias_base[(size_t)r * S_LEN + jt * 64 + nt * 16];
        mpre[nt * 4 + r] = mask_base[(size_t)r * S_LEN + jt * 64 + nt * 16];
      }
  };

  float lsum[4];
  f32x4 oacc[4];
  f32x4 zero = {0.f, 0.f, 0.f, 0.f};
#pragma unroll
  for (int r = 0; r < 4; ++r) lsum[r] = 0.f;
#pragma unroll
  for (int dt = 0; dt < 4; ++dt) oacc[dt] = zero;

  // prologue: stage tile 0, prefetch bias/mask tile 0
  STAGE(0, Ksm0, Vsm0);
  BM_PRE(0);

  for (int j = 0; j < S_LEN / 64; ++j) {
    __syncthreads();                 // tile j arrived in buf[cur]; all waves done
                                     // reading buf[cur^1] (their iter j-1)
    const int pu = j & 1;
    const unsigned short* Kc = pu ? Ksm1 : Ksm0;
    const unsigned short* Vc = pu ? Vsm1 : Vsm0;
    unsigned short* Kn = pu ? Ksm0 : Ksm1;
    unsigned short* Vn = pu ? Vsm0 : Vsm1;
    const int jn = (j + 1 < S_LEN / 64) ? j + 1 : j;

    // stage tile j+1 into the other buffer; latency hides under compute j
    STAGE(jn, Kn, Vn);

    // ---- S = Q K^T : q rows w*16+g*4+r, kv cols nt*16+c
    f32x4 sAcc[4];
#pragma unroll
    for (int nt = 0; nt < 4; ++nt) sAcc[nt] = zero;
#pragma unroll
    for (int ks = 0; ks < 2; ++ks)
#pragma unroll
      for (int nt = 0; nt < 4; ++nt) {
        int r = nt * 16 + c;
        int seg = (ks * 4 + g) ^ (r & 7);
        bf16x8 kF = *(const bf16x8*)((const char*)Kc + r * 128 + seg * 16);
        sAcc[nt] = __builtin_amdgcn_mfma_f32_16x16x32_bf16(qF[ks], kF, sAcc[nt], 0, 0, 0);
      }

    // ---- p = exp2(s + bias*C1 + mask*C2), m==0; per-lane partial row sums
#pragma unroll
    for (int r = 0; r < 4; ++r) {
      float pv[4];
#pragma unroll
      for (int nt = 0; nt < 4; ++nt) {
        float t = __builtin_fmaf(bpre[nt * 4 + r], C1,
                  __builtin_fmaf(mpre[nt * 4 + r], C2, sAcc[nt][r]));
        pv[nt] = __builtin_amdgcn_exp2f(t);
        sAcc[nt][r] = pv[nt];
      }
      lsum[r] += (pv[0] + pv[1]) + (pv[2] + pv[3]);
    }

    // ---- prefetch bias/mask for tile j+1 (bpre/mpre consumed above)
    BM_PRE(jn);

    // ---- P -> wave-private LDS (C-layout -> A-layout), NSEG8 swizzle on 16 rows
#pragma unroll
    for (int nt = 0; nt < 4; ++nt)
#pragma unroll
      for (int r = 0; r < 4; ++r) {
        int row_l = g * 4 + r;
        int kv = nt * 16 + c;
        int seg = (kv >> 3) ^ (row_l & 7);
        *(unsigned short*)(Pw + row_l * 128 + seg * 16 + (kv & 7) * 2) = f2bf(sAcc[nt][r]);
      }
    // wave-private region: no barrier needed (same-wave lgkmcnt ordering)

    // ---- O += P @ V
#pragma unroll
    for (int ks = 0; ks < 2; ++ks) {
      int segP = (ks * 4 + g) ^ (c & 7);         // row = c
      bf16x8 aP = *(const bf16x8*)(Pw + c * 128 + segP * 16);
#pragma unroll
      for (int dt = 0; dt < 4; ++dt) {
        int dr = dt * 16 + c;
        int segV = (ks * 4 + g) ^ (dr & 7);
        bf16x8 vF = *(const bf16x8*)((const char*)Vc + dr * 128 + segV * 16);
        oacc[dt] = __builtin_amdgcn_mfma_f32_16x16x32_bf16(aP, vF, oacc[dt], 0, 0, 0);
      }
    }
  }

  // ---- deferred l reduce across the 16 lanes sharing a row, then store
#pragma unroll
  for (int r = 0; r < 4; ++r) {
    float s = lsum[r];
    s += __shfl_xor(s, 1);
    s += __shfl_xor(s, 2);
    s += __shfl_xor(s, 4);
    s += __shfl_xor(s, 8);
    float inv = 1.f / s;
    int qg = q0 + w * 16 + g * 4 + r;
#pragma unroll
    for (int dt = 0; dt < 4; ++dt)
      Osm[(size_t)(b * S_LEN + qg) * INNER_DIM + h * D_HEAD + dt * 16 + c] =
          f2bf(oacc[dt][r] * inv);
  }
}

// ---------------------------------------------------------------- launch
extern "C" void kernel_launch(void* const* d_in, const int* in_sizes, int n_in,
                              void* d_out, int out_size, void* d_ws, size_t ws_size,
                              hipStream_t stream) {
  const float* query = (const float*)d_in[0];
  const float* key   = (const float*)d_in[1];
  const float* value = (const float*)d_in[2];
  const float* mask  = (const float*)d_in[3];
  const float* bias  = (const float*)d_in[4];
  const float* Wq = (const float*)d_in[5];
  const float* bq = (const float*)d_in[6];
  const float* Wk = (const float*)d_in[7];
  const float* bk = (const float*)d_in[8];
  const float* Wv = (const float*)d_in[9];
  const float* bv = (const float*)d_in[10];
  const float* Wo = (const float*)d_in[11];
  const float* bo = (const float*)d_in[12];

  const size_t NTOK   = (size_t)B_SZ * S_LEN;       // 4096
  const size_t SZ_ACT = NTOK * INNER_DIM;           // 4 Mi elems
  const size_t SZ_W   = (size_t)HID_DIM * INNER_DIM;

  unsigned short* ws  = (unsigned short*)d_ws;
  unsigned short* qb  = ws;
  unsigned short* kb  = qb + SZ_ACT;
  unsigned short* vb  = kb + SZ_ACT;
  unsigned short* Wqt = vb + SZ_ACT;
  unsigned short* Wkt = Wqt + SZ_W;
  unsigned short* Wvt = Wkt + SZ_W;
  unsigned short* Wot = Wvt + SZ_W;
  unsigned short* Qp  = Wot + SZ_W;
  unsigned short* Kp  = Qp + SZ_ACT;
  unsigned short* Vp  = Kp + SZ_ACT;                // [B][H][D][S]
  unsigned short* Ob  = Vp + SZ_ACT;

  int n4 = (int)(SZ_ACT / 4);
  int cblk = (n4 + 255) / 256;
  dim3 cgrid(cblk, 3);
  cast3_kernel<<<cgrid, 256, 0, stream>>>(query, key, value, qb, kb, vb, n4);

  dim3 tgrid(INNER_DIM / 32, HID_DIM / 32);
  transpose_cast_kernel<<<tgrid, 256, 0, stream>>>(Wq, Wqt, HID_DIM, INNER_DIM);
  transpose_cast_kernel<<<tgrid, 256, 0, stream>>>(Wk, Wkt, HID_DIM, INNER_DIM);
  transpose_cast_kernel<<<tgrid, 256, 0, stream>>>(Wv, Wvt, HID_DIM, INNER_DIM);
  transpose_cast_kernel<<<tgrid, 256, 0, stream>>>(Wo, Wot, INNER_DIM, HID_DIM);

  dim3 ggrid(NTOK / 128, INNER_DIM / 64, 3);        // (32,16,3)
  qkv_gemm_kernel<<<ggrid, 256, 0, stream>>>(qb, kb, vb, Wqt, Wkt, Wvt,
                                             bq, bk, bv, Qp, Kp, Vp);

  dim3 agrid(S_LEN / 64, N_HEAD, B_SZ);             // (32,16,2)
  attn_kernel<<<agrid, 256, 0, stream>>>(Qp, Kp, Vp, bias, mask, Ob);

  dim3 ogrid(NTOK / 128, HID_DIM / 64);
  out_gemm_kernel<<<ogrid, 256, 0, stream>>>(Ob, Wot, bo, (float*)d_out);
}

// Round 4
// 570.854 us; speedup vs baseline: 1.0132x; 1.0132x over previous
//
#include <hip/hip_runtime.h>
#include <cstdint>
#include <cstddef>

// Problem constants
#define B_SZ      2
#define S_LEN     2048
#define HID_DIM   1024
#define N_HEAD    16
#define D_HEAD    64
#define INNER_DIM 1024

// scale constants: scores = (s + bias)/8 + mask, softmax in exp2 space
// fold 0.125*log2(e) into Q at projection time; fused bias = bias*C1 + mask*C2
#define C1 0.18033688011112042f    /* 0.125 * log2(e) */
#define C2 1.44269504088896340736f /* log2(e) */

typedef __attribute__((ext_vector_type(8))) short bf16x8;   // 8 x bf16 (4 VGPRs)
typedef __attribute__((ext_vector_type(4))) float f32x4;    // MFMA 16x16 C/D

__device__ __forceinline__ unsigned short f2bf(float f) {
  unsigned int u = __float_as_uint(f);
  u += 0x7fffu + ((u >> 16) & 1u);
  return (unsigned short)(u >> 16);
}
__device__ __forceinline__ float bf2f(unsigned short u) {
  return __uint_as_float(((unsigned int)u) << 16);
}

// async global->LDS, 16B per lane; dest = wave-uniform base + lane*16
__device__ __forceinline__ void gload_lds16(const void* g, void* l) {
  __builtin_amdgcn_global_load_lds((const __attribute__((address_space(1))) void*)g,
                                   (__attribute__((address_space(3))) void*)l,
                                   16, 0, 0);
}

// ---------------------------------------------------------------- cast fp32->bf16 (x3)
__global__ void cast3_kernel(const float* __restrict__ i0, const float* __restrict__ i1,
                             const float* __restrict__ i2,
                             unsigned short* __restrict__ o0, unsigned short* __restrict__ o1,
                             unsigned short* __restrict__ o2, int n4) {
  int z = blockIdx.y;
  const float* in = (z == 0) ? i0 : (z == 1) ? i1 : i2;
  unsigned short* out = (z == 0) ? o0 : (z == 1) ? o1 : o2;
  int i = blockIdx.x * blockDim.x + threadIdx.x;
  if (i < n4) {
    float4 v = ((const float4*)in)[i];
    ushort4 o;
    o.x = f2bf(v.x); o.y = f2bf(v.y); o.z = f2bf(v.z); o.w = f2bf(v.w);
    ((ushort4*)out)[i] = o;
  }
}

// ------------------------------------------- transpose + cast: W[K][N] -> Wt[N][K] bf16
__global__ void transpose_cast_kernel(const float* __restrict__ in,
                                      unsigned short* __restrict__ out,
                                      int rows, int cols) {
  __shared__ float tile[32][33];
  int bx = blockIdx.x * 32;
  int by = blockIdx.y * 32;
  int tx = threadIdx.x & 31;
  int ty = threadIdx.x >> 5;
#pragma unroll
  for (int i = 0; i < 32; i += 8)
    tile[ty + i][tx] = in[(size_t)(by + ty + i) * cols + bx + tx];
  __syncthreads();
#pragma unroll
  for (int i = 0; i < 32; i += 8)
    out[(size_t)(bx + ty + i) * rows + by + tx] = f2bf(tile[tx][ty + i]);
}

// ---------------------------------------------------------------- GEMM core
// A: [M][1024] bf16 row-major.  Bt: [N][1024] bf16 row-major.
// Tile 128(M) x 128(N) x 64(K) (verified m97 geometry: 32 MFMA + 16 ds_read_b128
// per wave per K-step); 256 thr = 4 waves (2x2), wave does 64x64.
// LDS XOR-swizzle: 16B segment stored at seg ^ (row & 7).

// Merged Q/K/V projection GEMM. z = blockIdx.z selects problem.
// z<2: bf16 row-major out (z==0 scaled by C1).  z==2: V, store transposed [B][H][D][S].
__global__ __launch_bounds__(256, 2)
void qkv_gemm_kernel(const unsigned short* __restrict__ Aq,
                     const unsigned short* __restrict__ Ak,
                     const unsigned short* __restrict__ Av,
                     const unsigned short* __restrict__ Wq,
                     const unsigned short* __restrict__ Wk,
                     const unsigned short* __restrict__ Wv,
                     const float* __restrict__ bq,
                     const float* __restrict__ bk,
                     const float* __restrict__ bv,
                     unsigned short* __restrict__ Oq,
                     unsigned short* __restrict__ Ok,
                     unsigned short* __restrict__ Ov) {
  constexpr int K = 1024;
  __shared__ unsigned short Asm[128 * 64];
  __shared__ unsigned short Bsm[128 * 64];

  const int z = blockIdx.z;
  const unsigned short* A  = (z == 0) ? Aq : (z == 1) ? Ak : Av;
  const unsigned short* Bt = (z == 0) ? Wq : (z == 1) ? Wk : Wv;
  const float* bias        = (z == 0) ? bq : (z == 1) ? bk : bv;
  const float scale        = (z == 0) ? C1 : 1.0f;

  const int tid = threadIdx.x;
  const int lane = tid & 63;
  const int w = tid >> 6;
  const int wm = w & 1;
  const int wn = w >> 1;
  const int c = lane & 15;
  const int g = lane >> 4;
  const int m0 = blockIdx.x * 128;
  const int n0 = blockIdx.y * 128;

  f32x4 acc[4][4];
  f32x4 zero = {0.f, 0.f, 0.f, 0.f};
#pragma unroll
  for (int mt = 0; mt < 4; ++mt)
#pragma unroll
    for (int nt = 0; nt < 4; ++nt) acc[mt][nt] = zero;

  for (int kk = 0; kk < K / 64; ++kk) {
    __syncthreads();
    const int k0 = kk * 64;
#pragma unroll
    for (int it = 0; it < 4; ++it) {
      int slot = it * 256 + tid;
      int r = slot >> 3, sp = slot & 7, seg = sp ^ (r & 7);
      gload_lds16(A + (size_t)(m0 + r) * K + k0 + seg * 8,
                  (char*)Asm + (it * 256 + w * 64) * 16);
    }
#pragma unroll
    for (int it = 0; it < 4; ++it) {
      int slot = it * 256 + tid;
      int r = slot >> 3, sp = slot & 7, seg = sp ^ (r & 7);
      gload_lds16(Bt + (size_t)(n0 + r) * K + k0 + seg * 8,
                  (char*)Bsm + (it * 256 + w * 64) * 16);
    }
    __syncthreads();

#pragma unroll
    for (int ks = 0; ks < 2; ++ks) {
      bf16x8 aF[4];
#pragma unroll
      for (int mt = 0; mt < 4; ++mt) {
        int r = wm * 64 + mt * 16 + c;
        int seg = (ks * 4 + g) ^ (r & 7);
        aF[mt] = *(const bf16x8*)((const char*)Asm + r * 128 + seg * 16);
      }
#pragma unroll
      for (int nt = 0; nt < 4; ++nt) {
        int r = wn * 64 + nt * 16 + c;
        int seg = (ks * 4 + g) ^ (r & 7);
        bf16x8 bF = *(const bf16x8*)((const char*)Bsm + r * 128 + seg * 16);
#pragma unroll
        for (int mt = 0; mt < 4; ++mt)
          acc[mt][nt] = __builtin_amdgcn_mfma_f32_16x16x32_bf16(aF[mt], bF, acc[mt][nt], 0, 0, 0);
      }
    }
  }

#pragma unroll
  for (int nt = 0; nt < 4; ++nt) {
    int n_g = n0 + wn * 64 + nt * 16 + c;
    float bvv = bias[n_g];
#pragma unroll
    for (int mt = 0; mt < 4; ++mt) {
      int m_base = m0 + wm * 64 + mt * 16 + g * 4;
      if (z == 2) {
        int b = m_base >> 11;
        int s = m_base & 2047;
        int hh = n_g >> 6;
        int d = n_g & 63;
        ushort4 pk;
        pk.x = f2bf(acc[mt][nt][0] + bvv);
        pk.y = f2bf(acc[mt][nt][1] + bvv);
        pk.z = f2bf(acc[mt][nt][2] + bvv);
        pk.w = f2bf(acc[mt][nt][3] + bvv);
        *(ushort4*)(Ov + ((size_t)((b * N_HEAD + hh) * D_HEAD + d)) * S_LEN + s) = pk;
      } else {
        unsigned short* o = (z == 0) ? Oq : Ok;
#pragma unroll
        for (int r = 0; r < 4; ++r)
          o[(size_t)(m_base + r) * INNER_DIM + n_g] = f2bf((acc[mt][nt][r] + bvv) * scale);
      }
    }
  }
}

// Out-projection GEMM: fp32 out.  Same 128x128 tile.
__global__ __launch_bounds__(256, 2)
void out_gemm_kernel(const unsigned short* __restrict__ A,
                     const unsigned short* __restrict__ Bt,
                     const float* __restrict__ bias,
                     float* __restrict__ out) {
  constexpr int K = 1024;
  __shared__ unsigned short Asm[128 * 64];
  __shared__ unsigned short Bsm[128 * 64];

  const int tid = threadIdx.x;
  const int lane = tid & 63;
  const int w = tid >> 6;
  const int wm = w & 1;
  const int wn = w >> 1;
  const int c = lane & 15;
  const int g = lane >> 4;
  const int m0 = blockIdx.x * 128;
  const int n0 = blockIdx.y * 128;

  f32x4 acc[4][4];
  f32x4 zero = {0.f, 0.f, 0.f, 0.f};
#pragma unroll
  for (int mt = 0; mt < 4; ++mt)
#pragma unroll
    for (int nt = 0; nt < 4; ++nt) acc[mt][nt] = zero;

  for (int kk = 0; kk < K / 64; ++kk) {
    __syncthreads();
    const int k0 = kk * 64;
#pragma unroll
    for (int it = 0; it < 4; ++it) {
      int slot = it * 256 + tid;
      int r = slot >> 3, sp = slot & 7, seg = sp ^ (r & 7);
      gload_lds16(A + (size_t)(m0 + r) * K + k0 + seg * 8,
                  (char*)Asm + (it * 256 + w * 64) * 16);
    }
#pragma unroll
    for (int it = 0; it < 4; ++it) {
      int slot = it * 256 + tid;
      int r = slot >> 3, sp = slot & 7, seg = sp ^ (r & 7);
      gload_lds16(Bt + (size_t)(n0 + r) * K + k0 + seg * 8,
                  (char*)Bsm + (it * 256 + w * 64) * 16);
    }
    __syncthreads();

#pragma unroll
    for (int ks = 0; ks < 2; ++ks) {
      bf16x8 aF[4];
#pragma unroll
      for (int mt = 0; mt < 4; ++mt) {
        int r = wm * 64 + mt * 16 + c;
        int seg = (ks * 4 + g) ^ (r & 7);
        aF[mt] = *(const bf16x8*)((const char*)Asm + r * 128 + seg * 16);
      }
#pragma unroll
      for (int nt = 0; nt < 4; ++nt) {
        int r = wn * 64 + nt * 16 + c;
        int seg = (ks * 4 + g) ^ (r & 7);
        bf16x8 bF = *(const bf16x8*)((const char*)Bsm + r * 128 + seg * 16);
#pragma unroll
        for (int mt = 0; mt < 4; ++mt)
          acc[mt][nt] = __builtin_amdgcn_mfma_f32_16x16x32_bf16(aF[mt], bF, acc[mt][nt], 0, 0, 0);
      }
    }
  }

#pragma unroll
  for (int nt = 0; nt < 4; ++nt) {
    int n_g = n0 + wn * 64 + nt * 16 + c;
    float bvv = bias[n_g];
#pragma unroll
    for (int mt = 0; mt < 4; ++mt) {
      int m_base = m0 + wm * 64 + mt * 16 + g * 4;
#pragma unroll
      for (int r = 0; r < 4; ++r)
        out[(size_t)(m_base + r) * HID_DIM + n_g] = acc[mt][nt][r] + bvv;
    }
  }
}

// ---------------------------------------------------------------- flash attention
// BATCH-FUSED: block (q0,h) processes BOTH batches; the bias tile (batch-
// independent, the dominant HBM stream at 268 MB) is loaded ONCE into registers
// and used for both batches' scores -> bias HBM traffic is exactly 1x and each
// bias-load latency window covers 2x compute.
// q-tile 64, kv-tile 64, 256 thr = 4 waves (wave w owns q rows w*16..+15).
// LDS: K 2batch x dbuf x 8K = 32K; V same 32K; P 8K (reused across batches)
// = 72 KB -> 2 blocks/CU (R2/R3 showed >2 blocks/CU buys nothing here).
// Softmax: m==0 (scores tightly bounded; shift-invariance => exact), deferred
// l-reduce -> zero cross-lane ops in the k-loop.  bias+mask fused into f0/f1
// registers at iter top so the next-tile prefetch issues with ~full-iter
// latency coverage.
__global__ __launch_bounds__(256, 2)
void attn_kernel(const unsigned short* __restrict__ Qp,
                 const unsigned short* __restrict__ Kp,
                 const unsigned short* __restrict__ Vp,
                 const float* __restrict__ bias,   // [1][H][S][S]
                 const float* __restrict__ mask,   // [B][1][S][S]
                 unsigned short* __restrict__ Osm) {
  __shared__ unsigned short Ksm[2][2][64 * 64];   // [buf][batch][kv][d] NSEG8  8 KB ea
  __shared__ unsigned short Vsm[2][2][64 * 64];   // [buf][batch][d][kv] NSEG8  8 KB ea
  __shared__ unsigned short Psm[64 * 64];         // [q][kv] wave-private       8 KB

  const int tid = threadIdx.x;
  const int lane = tid & 63;
  const int w = tid >> 6;           // wave 0..3
  const int c = lane & 15;
  const int g = lane >> 4;
  const int q0 = blockIdx.x * 64;
  const int h = blockIdx.y;

  char* Pw = (char*)Psm + w * 2048;     // wave-private 16 rows x 128 B

  // Q fragments for both batches (A-layout: m=c, k=g*8+j), rows w*16+c
  bf16x8 qF[2][2];
#pragma unroll
  for (int bb = 0; bb < 2; ++bb) {
    size_t row = (size_t)(bb * S_LEN + q0 + w * 16 + c);
#pragma unroll
    for (int ks = 0; ks < 2; ++ks)
      qF[bb][ks] = *(const bf16x8*)(Qp + row * INNER_DIM + h * D_HEAD + ks * 32 + g * 8);
  }

  // per-lane bias/mask bases in CONSUME layout: row = g*4 (+r), col = c (+nt*16)
  const float* bias_base  = bias + ((size_t)h * S_LEN + q0 + w * 16 + g * 4) * S_LEN + c;
  const float* mask_base0 = mask + ((size_t)(0 * S_LEN) + q0 + w * 16 + g * 4) * S_LEN + c;
  const float* mask_base1 = mask + ((size_t)(1 * S_LEN) + q0 + w * 16 + g * 4) * S_LEN + c;

  // j-invariant staging sources (swizzled source addr, linear LDS dest)
  const unsigned short* kSrc[2][2];
  const unsigned short* vSrc[2][2];
#pragma unroll
  for (int bb = 0; bb < 2; ++bb)
#pragma unroll
    for (int it = 0; it < 2; ++it) {
      int slot = it * 256 + tid;
      int r = slot >> 3, sp = slot & 7, seg = sp ^ (r & 7);
      kSrc[bb][it] = Kp + (size_t)(bb * S_LEN + r) * INNER_DIM + h * D_HEAD + seg * 8;
      vSrc[bb][it] = Vp + ((size_t)((bb * N_HEAD + h) * D_HEAD + r)) * S_LEN + seg * 8;
    }

  auto STAGE = [&](int jt, int pb) {
#pragma unroll
    for (int bb = 0; bb < 2; ++bb)
#pragma unroll
      for (int it = 0; it < 2; ++it) {
        gload_lds16(kSrc[bb][it] + (size_t)jt * (64 * INNER_DIM),
                    (char*)Ksm[pb][bb] + (it * 256 + w * 64) * 16);
        gload_lds16(vSrc[bb][it] + jt * 64,
                    (char*)Vsm[pb][bb] + (it * 256 + w * 64) * 16);
      }
  };

  float bpre[16], mpre[2][16];          // bias/mask prefetch, one tile ahead
  auto BM_PRE = [&](int jt) {
#pragma unroll
    for (int nt = 0; nt < 4; ++nt)
#pragma unroll
      for (int r = 0; r < 4; ++r) {
        size_t off = (size_t)r * S_LEN + jt * 64 + nt * 16;
        bpre[nt * 4 + r]    = bias_base[off];
        mpre[0][nt * 4 + r] = mask_base0[off];
        mpre[1][nt * 4 + r] = mask_base1[off];
      }
  };

  float lsum[2][4];
  f32x4 oacc[2][4];
  f32x4 zero = {0.f, 0.f, 0.f, 0.f};
#pragma unroll
  for (int bb = 0; bb < 2; ++bb)
#pragma unroll
    for (int r = 0; r < 4; ++r) { lsum[bb][r] = 0.f; oacc[bb][r] = zero; }

  // prologue: stage tile 0 into buf 0, prefetch bias/mask tile 0
  STAGE(0, 0);
  BM_PRE(0);

  for (int j = 0; j < S_LEN / 64; ++j) {
    __syncthreads();                 // tile j arrived in buf[pu]; all waves done
                                     // reading buf[pu^1] (their iter j-1)
    const int pu = j & 1;
    const int jn = (j + 1 < S_LEN / 64) ? j + 1 : j;

    // stage tile j+1 into the other buffer; latency hides under compute j
    STAGE(jn, pu ^ 1);

    // ---- fold bias+mask into per-batch fused adders, then immediately issue
    // next-tile prefetch (bpre/mpre free after this; ~full-iter coverage)
    float fuse[2][16];
#pragma unroll
    for (int i = 0; i < 16; ++i) {
      float bb_ = bpre[i] * C1;
      fuse[0][i] = __builtin_fmaf(mpre[0][i], C2, bb_);
      fuse[1][i] = __builtin_fmaf(mpre[1][i], C2, bb_);
    }
    BM_PRE(jn);

#pragma unroll
    for (int bb = 0; bb < 2; ++bb) {
      // ---- S = Q K^T : q rows w*16+g*4+r, kv cols nt*16+c
      f32x4 sAcc[4];
#pragma unroll
      for (int nt = 0; nt < 4; ++nt) sAcc[nt] = zero;
#pragma unroll
      for (int ks = 0; ks < 2; ++ks)
#pragma unroll
        for (int nt = 0; nt < 4; ++nt) {
          int r = nt * 16 + c;
          int seg = (ks * 4 + g) ^ (r & 7);
          bf16x8 kF = *(const bf16x8*)((const char*)Ksm[pu][bb] + r * 128 + seg * 16);
          sAcc[nt] = __builtin_amdgcn_mfma_f32_16x16x32_bf16(qF[bb][ks], kF, sAcc[nt], 0, 0, 0);
        }

      // ---- p = exp2(s + fuse), m==0; per-lane partial row sums
#pragma unroll
      for (int r = 0; r < 4; ++r) {
        float pv[4];
#pragma unroll
        for (int nt = 0; nt < 4; ++nt) {
          float t = sAcc[nt][r] + fuse[bb][nt * 4 + r];
          pv[nt] = __builtin_amdgcn_exp2f(t);
          sAcc[nt][r] = pv[nt];
        }
        lsum[bb][r] += (pv[0] + pv[1]) + (pv[2] + pv[3]);
      }

      // ---- P -> wave-private LDS (C-layout -> A-layout), NSEG8 swizzle
      // (safe to overwrite across batches: same-wave DS ops execute in order)
#pragma unroll
      for (int nt = 0; nt < 4; ++nt)
#pragma unroll
        for (int r = 0; r < 4; ++r) {
          int row_l = g * 4 + r;
          int kv = nt * 16 + c;
          int seg = (kv >> 3) ^ (row_l & 7);
          *(unsigned short*)(Pw + row_l * 128 + seg * 16 + (kv & 7) * 2) = f2bf(sAcc[nt][r]);
        }

      // ---- O += P @ V
#pragma unroll
      for (int ks = 0; ks < 2; ++ks) {
        int segP = (ks * 4 + g) ^ (c & 7);       // row = c
        bf16x8 aP = *(const bf16x8*)(Pw + c * 128 + segP * 16);
#pragma unroll
        for (int dt = 0; dt < 4; ++dt) {
          int dr = dt * 16 + c;
          int segV = (ks * 4 + g) ^ (dr & 7);
          bf16x8 vF = *(const bf16x8*)((const char*)Vsm[pu][bb] + dr * 128 + segV * 16);
          oacc[bb][dt] = __builtin_amdgcn_mfma_f32_16x16x32_bf16(aP, vF, oacc[bb][dt], 0, 0, 0);
        }
      }
    }
  }

  // ---- deferred l reduce across the 16 lanes sharing a row, then store
#pragma unroll
  for (int bb = 0; bb < 2; ++bb)
#pragma unroll
    for (int r = 0; r < 4; ++r) {
      float s = lsum[bb][r];
      s += __shfl_xor(s, 1);
      s += __shfl_xor(s, 2);
      s += __shfl_xor(s, 4);
      s += __shfl_xor(s, 8);
      float inv = 1.f / s;
      int qg = q0 + w * 16 + g * 4 + r;
#pragma unroll
      for (int dt = 0; dt < 4; ++dt)
        Osm[(size_t)(bb * S_LEN + qg) * INNER_DIM + h * D_HEAD + dt * 16 + c] =
            f2bf(oacc[bb][dt][r] * inv);
    }
}

// ---------------------------------------------------------------- launch
extern "C" void kernel_launch(void* const* d_in, const int* in_sizes, int n_in,
                              void* d_out, int out_size, void* d_ws, size_t ws_size,
                              hipStream_t stream) {
  const float* query = (const float*)d_in[0];
  const float* key   = (const float*)d_in[1];
  const float* value = (const float*)d_in[2];
  const float* mask  = (const float*)d_in[3];
  const float* bias  = (const float*)d_in[4];
  const float* Wq = (const float*)d_in[5];
  const float* bq = (const float*)d_in[6];
  const float* Wk = (const float*)d_in[7];
  const float* bk = (const float*)d_in[8];
  const float* Wv = (const float*)d_in[9];
  const float* bv = (const float*)d_in[10];
  const float* Wo = (const float*)d_in[11];
  const float* bo = (const float*)d_in[12];

  const size_t NTOK   = (size_t)B_SZ * S_LEN;       // 4096
  const size_t SZ_ACT = NTOK * INNER_DIM;           // 4 Mi elems
  const size_t SZ_W   = (size_t)HID_DIM * INNER_DIM;

  unsigned short* ws  = (unsigned short*)d_ws;
  unsigned short* qb  = ws;
  unsigned short* kb  = qb + SZ_ACT;
  unsigned short* vb  = kb + SZ_ACT;
  unsigned short* Wqt = vb + SZ_ACT;
  unsigned short* Wkt = Wqt + SZ_W;
  unsigned short* Wvt = Wkt + SZ_W;
  unsigned short* Wot = Wvt + SZ_W;
  unsigned short* Qp  = Wot + SZ_W;
  unsigned short* Kp  = Qp + SZ_ACT;
  unsigned short* Vp  = Kp + SZ_ACT;                // [B][H][D][S]
  unsigned short* Ob  = Vp + SZ_ACT;

  int n4 = (int)(SZ_ACT / 4);
  int cblk = (n4 + 255) / 256;
  dim3 cgrid(cblk, 3);
  cast3_kernel<<<cgrid, 256, 0, stream>>>(query, key, value, qb, kb, vb, n4);

  dim3 tgrid(INNER_DIM / 32, HID_DIM / 32);
  transpose_cast_kernel<<<tgrid, 256, 0, stream>>>(Wq, Wqt, HID_DIM, INNER_DIM);
  transpose_cast_kernel<<<tgrid, 256, 0, stream>>>(Wk, Wkt, HID_DIM, INNER_DIM);
  transpose_cast_kernel<<<tgrid, 256, 0, stream>>>(Wv, Wvt, HID_DIM, INNER_DIM);
  transpose_cast_kernel<<<tgrid, 256, 0, stream>>>(Wo, Wot, INNER_DIM, HID_DIM);

  dim3 ggrid(NTOK / 128, INNER_DIM / 128, 3);       // (32,8,3)
  qkv_gemm_kernel<<<ggrid, 256, 0, stream>>>(qb, kb, vb, Wqt, Wkt, Wvt,
                                             bq, bk, bv, Qp, Kp, Vp);

  dim3 agrid(S_LEN / 64, N_HEAD);                   // (32,16) batch-fused
  attn_kernel<<<agrid, 256, 0, stream>>>(Qp, Kp, Vp, bias, mask, Ob);

  dim3 ogrid(NTOK / 128, HID_DIM / 128);
  out_gemm_kernel<<<ogrid, 256, 0, stream>>>(Ob, Wot, bo, (float*)d_out);
}